// Round 12
// baseline (22.187 us; speedup 1.0000x reference)
//
#include <hip/hip_runtime.h>
#include <math.h>
#include <float.h>

#define NS 8
#define NA 64
#define NP 32
#define NT 80
#define NK 6
#define NAG (NS*NA)           // 512 agents

// single-instruction v_sqrt_f32 (~1 ULP): ADE feeds comparisons with wide margins
#define FSQRT(x) __builtin_amdgcn_sqrtf(x)

__device__ __forceinline__ float pdist(float ax, float ay, float bx, float by) {
    float dx = ax - bx, dy = ay - by;
    return FSQRT(fmaf(dx, dx, dy*dy));
}

// out layout offsets (floats)
#define BASE1 ((size_t)NS*NT*NA*NK*2)          // yaw after xy
#define BASE2 (BASE1 + (size_t)NS*NT*NA*NK)    // spd
#define BASE3 (BASE2 + (size_t)NS*NT*NA*NK)    // scores
#define BASE4 (BASE3 + (size_t)NS*NA*NK)       // valid

// ============ fully fused: ADE + MTR NMS + MPA NMS + softmax + write ============
// 512 threads/block (8 waves) -> 2 blocks/CU = 4 waves/SIMD.
__global__ __launch_bounds__(512) void k_fused(
    const void* __restrict__ valid_raw,
    const float* __restrict__ scores,
    const float* __restrict__ trajs,
    const float* __restrict__ atype,
    float* __restrict__ out)
{
    const int bid = blockIdx.x;
    const int blk = (bid & 7) * 64 + (bid >> 3);   // XCD-aware agent swizzle
    const int s = blk >> 6;
    const int a = blk & 63;
    const int tid = threadIdx.x;
    const int lane = tid & 63;
    const int p = lane & 31;

    // xy points: row = 17 float4 (32 pts as 16 float4 + 1 pad) -> 272B stride,
    // 16B-aligned rows for ds_read_b128
    __shared__ float4 s4[NT][17];        // 21760 B
    __shared__ float sade[NP][NP];       // 4096 B full ADE matrix
    __shared__ unsigned wloc[NP];        // MTR within rows (incl diagonal)

    if (tid < NP) wloc[tid] = 1u << tid;

    // ---- prefetch tail inputs (phase C runs on waves 0-3) ----
    const unsigned* vw = (const unsigned*)valid_raw;
    unsigned u0 = vw[lane], u1 = vw[lane + 64];
    float sc = scores[blk*NP + p];
    const float a0 = atype[blk*3+0], a1 = atype[blk*3+1], a2 = atype[blk*3+2];
    const float thrM = a0*3.5f + a1*1.0f + a2*1.75f;
    const float thrQ = a0*2.5f + a1*1.0f + a2*1.5f;

    // ---- phase A: stage xy (read full float4 lines, coalesced) ----
    const float4* tg4 = (const float4*)trajs + (size_t)blk * NP * NT;
    #pragma unroll
    for (int rep = 0; rep < 5; ++rep) {
        int l = tid + rep*512;           // 2560 records
        int pp = l / NT, t = l - pp*NT;
        float4 v = tg4[l];
        ((float2*)&s4[t][0])[pp] = make_float2(v.x, v.y);
    }
    __syncthreads();

    // ---- phase B: k=4 register tiles -- 2 float4 loads/side, 16 dists (4B LDS/pair-t) ----
    // 28 off-diag group pairs + 8 diagonal groups, x4 t-slices = 144 workers.
    // Per-pair sum order identical to R8-R11 (ascending t per slice, quad-fold).
    if (tid < 144) {
        const int tile = tid >> 2, slice = tid & 3;
        const int tbase = slice * 20;
        const int qb = lane & ~3;
        const float inv = 1.0f / (float)NT;
#define FOLD(acc) ((((acc) + __shfl((acc), qb+1)) + __shfl((acc), qb+2)) + __shfl((acc), qb+3))
#define EMIT(F, I, J) { float ade = (F)*inv; sade[I][J] = ade; sade[J][I] = ade; \
        if (ade < thrM) { atomicOr(&wloc[I], 1u<<(J)); atomicOr(&wloc[J], 1u<<(I)); } }
        if (tile < 28) {
            // group pair (gi,gj), gi<gj over 8 groups of 4 points
            float fs = sqrtf((float)(1 + 8*tile));     // exact at group starts
            int gj = (int)((1.0f + fs) * 0.5f);
            int gi = tile - ((gj*(gj-1)) >> 1);
            const int bi4 = 4*gi, bj4 = 4*gj;
            float c00=0,c01=0,c02=0,c03=0, c10=0,c11=0,c12=0,c13=0;
            float c20=0,c21=0,c22=0,c23=0, c30=0,c31=0,c32=0,c33=0;
            for (int tt = 0; tt < 20; ++tt) {
                int t = tbase + tt;
                float4 fa0 = s4[t][2*gi], fa1 = s4[t][2*gi+1];
                float4 fb0 = s4[t][2*gj], fb1 = s4[t][2*gj+1];
                c00 += pdist(fa0.x,fa0.y, fb0.x,fb0.y);
                c01 += pdist(fa0.x,fa0.y, fb0.z,fb0.w);
                c02 += pdist(fa0.x,fa0.y, fb1.x,fb1.y);
                c03 += pdist(fa0.x,fa0.y, fb1.z,fb1.w);
                c10 += pdist(fa0.z,fa0.w, fb0.x,fb0.y);
                c11 += pdist(fa0.z,fa0.w, fb0.z,fb0.w);
                c12 += pdist(fa0.z,fa0.w, fb1.x,fb1.y);
                c13 += pdist(fa0.z,fa0.w, fb1.z,fb1.w);
                c20 += pdist(fa1.x,fa1.y, fb0.x,fb0.y);
                c21 += pdist(fa1.x,fa1.y, fb0.z,fb0.w);
                c22 += pdist(fa1.x,fa1.y, fb1.x,fb1.y);
                c23 += pdist(fa1.x,fa1.y, fb1.z,fb1.w);
                c30 += pdist(fa1.z,fa1.w, fb0.x,fb0.y);
                c31 += pdist(fa1.z,fa1.w, fb0.z,fb0.w);
                c32 += pdist(fa1.z,fa1.w, fb1.x,fb1.y);
                c33 += pdist(fa1.z,fa1.w, fb1.z,fb1.w);
            }
            float f00=FOLD(c00), f01=FOLD(c01), f02=FOLD(c02), f03=FOLD(c03);
            float f10=FOLD(c10), f11=FOLD(c11), f12=FOLD(c12), f13=FOLD(c13);
            float f20=FOLD(c20), f21=FOLD(c21), f22=FOLD(c22), f23=FOLD(c23);
            float f30=FOLD(c30), f31=FOLD(c31), f32=FOLD(c32), f33=FOLD(c33);
            if (slice == 0) {
                EMIT(f00, bi4+0, bj4+0) EMIT(f01, bi4+0, bj4+1)
                EMIT(f02, bi4+0, bj4+2) EMIT(f03, bi4+0, bj4+3)
                EMIT(f10, bi4+1, bj4+0) EMIT(f11, bi4+1, bj4+1)
                EMIT(f12, bi4+1, bj4+2) EMIT(f13, bi4+1, bj4+3)
                EMIT(f20, bi4+2, bj4+0) EMIT(f21, bi4+2, bj4+1)
                EMIT(f22, bi4+2, bj4+2) EMIT(f23, bi4+2, bj4+3)
                EMIT(f30, bi4+3, bj4+0) EMIT(f31, bi4+3, bj4+1)
                EMIT(f32, bi4+3, bj4+2) EMIT(f33, bi4+3, bj4+3)
            }
        } else {
            // diagonal group g: 6 within-group pairs
            const int g = tile - 28;
            const int b4 = 4*g;
            float d01=0,d02=0,d03=0,d12=0,d13=0,d23=0;
            for (int tt = 0; tt < 20; ++tt) {
                int t = tbase + tt;
                float4 fa0 = s4[t][2*g], fa1 = s4[t][2*g+1];
                d01 += pdist(fa0.x,fa0.y, fa0.z,fa0.w);
                d02 += pdist(fa0.x,fa0.y, fa1.x,fa1.y);
                d03 += pdist(fa0.x,fa0.y, fa1.z,fa1.w);
                d12 += pdist(fa0.z,fa0.w, fa1.x,fa1.y);
                d13 += pdist(fa0.z,fa0.w, fa1.z,fa1.w);
                d23 += pdist(fa1.x,fa1.y, fa1.z,fa1.w);
            }
            float g01=FOLD(d01), g02=FOLD(d02), g03=FOLD(d03);
            float g12=FOLD(d12), g13=FOLD(d13), g23=FOLD(d23);
            if (slice == 0) {
                EMIT(g01, b4+0, b4+1) EMIT(g02, b4+0, b4+2) EMIT(g03, b4+0, b4+3)
                EMIT(g12, b4+1, b4+2) EMIT(g13, b4+1, b4+3) EMIT(g23, b4+2, b4+3)
            }
        }
#undef EMIT
#undef FOLD
    }
    __syncthreads();

    // ---- phase C + outputs: waves 0-3 only (waves 4-7 have no output work) ----
    if (tid < 256) {
        // valid[] encoding detection (u8 bool / i32 / f32)
        bool fHit = (u0 == 0x3F800000u) || (u1 == 0x3F800000u);
        int nz0 = ((u0&0xFFu)!=0)+((u0&0xFF00u)!=0)+((u0&0xFF0000u)!=0)+((u0&0xFF000000u)!=0);
        int nz1 = ((u1&0xFFu)!=0)+((u1&0xFF00u)!=0)+((u1&0xFF0000u)!=0)+((u1&0xFF000000u)!=0);
        bool isF = __any(fHit), multi = __any(nz0 >= 2 || nz1 >= 2);
        int vflag;
        if (isF)        vflag = (((const float*)valid_raw)[blk] != 0.0f);
        else if (multi) vflag = (((const unsigned char*)valid_raw)[blk] != 0);
        else            vflag = (((const int*)valid_raw)[blk] != 0);

        unsigned wl = wloc[p];

        // greedy MTR scan: 5-level fmax reduce + ballot/ffs argmax (first-index tie-break)
        float carry = sc;
        int sel_0, sel_1, sel_2, sel_3, sel_4, sel_5;
#define GREEDY(SK) { \
        float vv = carry; \
        _Pragma("unroll") \
        for (int off = 16; off; off >>= 1) vv = fmaxf(vv, __shfl_xor(vv, off)); \
        unsigned long long mba = __ballot(carry == vv); \
        int bi = __ffsll((long long)mba) - 1; \
        SK = bi; \
        unsigned rbi = __shfl(wl, bi); \
        carry = (p == bi) ? -1.0f : (((rbi >> p) & 1u) ? carry*0.01f : carry); }
        GREEDY(sel_0) GREEDY(sel_1) GREEDY(sel_2) GREEDY(sel_3) GREEDY(sel_4) GREEDY(sel_5)
#undef GREEDY

        float q0 = __shfl(sc, sel_0), q1 = __shfl(sc, sel_1), q2 = __shfl(sc, sel_2);
        float q3 = __shfl(sc, sel_3), q4 = __shfl(sc, sel_4), q5 = __shfl(sc, sel_5);

        // MPA 6x6 within from LDS ADE matrix (lanes 0-14 of each wave, one pair each)
        int ii = (lane<5)?0 : (lane<9)?1 : (lane<12)?2 : (lane<14)?3 : 4;
        int jj = lane - ((ii==0)?-1 : (ii==1)?3 : (ii==2)?6 : (ii==3)?8 : 9);
        jj = (jj < 0) ? 0 : (jj > 5 ? 5 : jj);
        int pi = (ii==0)?sel_0:(ii==1)?sel_1:(ii==2)?sel_2:(ii==3)?sel_3:(ii==4)?sel_4:sel_5;
        int pj = (jj==0)?sel_0:(jj==1)?sel_1:(jj==2)?sel_2:(jj==3)?sel_3:(jj==4)?sel_4:sel_5;
        float ade15 = sade[pi][pj];
        bool within = (lane < 15) && (ade15 < thrQ);
        unsigned long long bal = __ballot(within);
#define B(i) ((unsigned)((bal >> (i)) & 1ull))
        unsigned w6_0 = (B(0)<<1)|(B(1)<<2)|(B(2)<<3)|(B(3)<<4)|(B(4)<<5);
        unsigned w6_1 = (B(0)<<0)|(B(5)<<2)|(B(6)<<3)|(B(7)<<4)|(B(8)<<5);
        unsigned w6_2 = (B(1)<<0)|(B(5)<<1)|(B(9)<<3)|(B(10)<<4)|(B(11)<<5);
        unsigned w6_3 = (B(2)<<0)|(B(6)<<1)|(B(9)<<2)|(B(12)<<4)|(B(13)<<5);
        unsigned w6_4 = (B(3)<<0)|(B(7)<<1)|(B(10)<<2)|(B(12)<<3)|(B(14)<<5);
        unsigned w6_5 = (B(4)<<0)|(B(8)<<1)|(B(11)<<2)|(B(13)<<3)|(B(14)<<4);
#undef B

        // stable ranks (argsort(-q), ties -> lower index)
#define GE(x,y) ((x) >= (y))
        bool a01=GE(q0,q1), a02=GE(q0,q2), a03=GE(q0,q3), a04=GE(q0,q4), a05=GE(q0,q5);
        bool a12=GE(q1,q2), a13=GE(q1,q3), a14=GE(q1,q4), a15=GE(q1,q5);
        bool a23=GE(q2,q3), a24=GE(q2,q4), a25=GE(q2,q5);
        bool a34=GE(q3,q4), a35=GE(q3,q5);
        bool a45=GE(q4,q5);
#undef GE
        int r0 = (!a01)+(!a02)+(!a03)+(!a04)+(!a05);
        int r1 = a01+(!a12)+(!a13)+(!a14)+(!a15);
        int r2 = a02+a12+(!a23)+(!a24)+(!a25);
        int r3 = a03+a13+a23+(!a34)+(!a35);
        int r4 = a04+a14+a24+a34+(!a45);
        int r5 = a05+a15+a25+a35+a45;

        // serial MPA scan, exact semantics, all-scalar
        const float sum6 = q0+q1+q2+q3+q4+q5;
        const float supv = 0.001f * sum6;
#define STEP(m) { \
        float ck = (r0==m)?q0:(r1==m)?q1:(r2==m)?q2:(r3==m)?q3:(r4==m)?q4:q5; \
        unsigned wk = (r0==m)?w6_0:(r1==m)?w6_1:(r2==m)?w6_2:(r3==m)?w6_3:(r4==m)?w6_4:w6_5; \
        bool sup = (((wk>>0)&1u)&&(q0>ck))||(((wk>>1)&1u)&&(q1>ck))||(((wk>>2)&1u)&&(q2>ck)) \
                 ||(((wk>>3)&1u)&&(q3>ck))||(((wk>>4)&1u)&&(q4>ck))||(((wk>>5)&1u)&&(q5>ck)); \
        bool go = vflag && sup; \
        q0 = (go&&(r0==m))?supv:q0; q1 = (go&&(r1==m))?supv:q1; q2 = (go&&(r2==m))?supv:q2; \
        q3 = (go&&(r3==m))?supv:q3; q4 = (go&&(r4==m))?supv:q4; q5 = (go&&(r5==m))?supv:q5; }
        STEP(0) STEP(1) STEP(2) STEP(3) STEP(4) STEP(5)
#undef STEP

        // softmax(1.25*ln q) via fast log/exp (outputs have 1.82 absmax margin)
        float g0 = __logf(q0)*1.25f, g1 = __logf(q1)*1.25f, g2 = __logf(q2)*1.25f;
        float g3 = __logf(q3)*1.25f, g4 = __logf(q4)*1.25f, g5 = __logf(q5)*1.25f;
        float mx = fmaxf(fmaxf(fmaxf(g0,g1),fmaxf(g2,g3)),fmaxf(g4,g5));
        float e0 = __expf(g0-mx), e1 = __expf(g1-mx), e2 = __expf(g2-mx);
        float e3 = __expf(g3-mx), e4 = __expf(g4-mx), e5 = __expf(g5-mx);
        float es = e0+e1+e2+e3+e4+e5;

        if (tid < NK) {       // wave 0: scores output
            float fv = (lane==0)?e0:(lane==1)?e1:(lane==2)?e2:(lane==3)?e3:(lane==4)?e4:e5;
            out[BASE3 + (size_t)blk*NK + lane] = fv / es;
        }
        if (tid < NT)         // waves 0-1: valid output
            out[BASE4 + (size_t)(s*NT + tid)*NA + a] = vflag ? 1.0f : 0.0f;

        // ---- phase D: traj outputs (sel in wave-uniform regs); gather from
        //      global (L2-hot from phase A) ----
        if (tid < 3*NT) {
            int t = tid / 3, kp = tid - t*3;
            int k0 = kp*2;
            int s0sel = (kp==0)?sel_0:(kp==1)?sel_2:sel_4;
            int s1sel = (kp==0)?sel_1:(kp==1)?sel_3:sel_5;
            float4 v0 = tg4[(size_t)s0sel*NT + t];
            float4 v1 = tg4[(size_t)s1sel*NT + t];
            size_t ob = (((size_t)(s*NT + t)*NA + a)*NK + k0);   // float2-unit index (even)
            *(float4*)((float2*)out + ob) = make_float4(v0.x, v0.y, v1.x, v1.y);
            *(float2*)(out + BASE1 + ob) = make_float2(v0.z, v1.z);
            *(float2*)(out + BASE2 + ob) = make_float2(v0.w, v1.w);
        }
    }
}

extern "C" void kernel_launch(void* const* d_in, const int* in_sizes, int n_in,
                              void* d_out, int out_size, void* d_ws, size_t ws_size,
                              hipStream_t stream) {
    const void*  valid  = d_in[0];
    const float* scores = (const float*)d_in[1];
    const float* trajs  = (const float*)d_in[2];
    const float* atype  = (const float*)d_in[3];
    k_fused<<<NAG, 512, 0, stream>>>(valid, scores, trajs, atype, (float*)d_out);
}

// Round 13
// 18.409 us; speedup vs baseline: 1.2052x; 1.2052x over previous
//
#include <hip/hip_runtime.h>
#include <math.h>
#include <float.h>

#define NS 8
#define NA 64
#define NP 32
#define NT 80
#define NK 6
#define NAG (NS*NA)           // 512 agents
#define PAIRS 496             // 32*31/2

// single-instruction v_sqrt_f32 (~1 ULP): ADE feeds comparisons with wide margins
#define FSQRT(x) __builtin_amdgcn_sqrtf(x)

// out layout offsets (floats)
#define BASE1 ((size_t)NS*NT*NA*NK*2)          // yaw after xy
#define BASE2 (BASE1 + (size_t)NS*NT*NA*NK)    // spd
#define BASE3 (BASE2 + (size_t)NS*NT*NA*NK)    // scores
#define BASE4 (BASE3 + (size_t)NS*NA*NK)       // valid

// ============ fully fused: ADE + MTR NMS + MPA NMS + softmax + write ============
// 512 threads/block (8 waves) -> 2 blocks/CU = 4 waves/SIMD.
__global__ __launch_bounds__(512) void k_fused(
    const void* __restrict__ valid_raw,
    const float* __restrict__ scores,
    const float* __restrict__ trajs,
    const float* __restrict__ atype,
    float* __restrict__ out)
{
    const int bid = blockIdx.x;
    const int blk = (bid & 7) * 64 + (bid >> 3);   // XCD-aware agent swizzle
    const int s = blk >> 6;
    const int a = blk & 63;
    const int tid = threadIdx.x;
    const int lane = tid & 63;
    const int p = lane & 31;

    __shared__ float2 sxy[NT][NP + 1];   // 21120 B  xy only
    __shared__ float sade[NP][NP];       // 4096 B full ADE matrix
    __shared__ unsigned wloc[NP];        // MTR within rows (incl diagonal)

    if (tid < NP) wloc[tid] = 1u << tid;

    // ---- prefetch tail inputs (phase C runs on waves 0-3) ----
    const unsigned* vw = (const unsigned*)valid_raw;
    unsigned u0 = vw[lane], u1 = vw[lane + 64];
    float sc = scores[blk*NP + p];
    const float a0 = atype[blk*3+0], a1 = atype[blk*3+1], a2 = atype[blk*3+2];
    const float thrM = a0*3.5f + a1*1.0f + a2*1.75f;
    const float thrQ = a0*2.5f + a1*1.0f + a2*1.5f;

    // ---- phase A: stage xy (read full float4 lines, coalesced) ----
    const float4* tg4 = (const float4*)trajs + (size_t)blk * NP * NT;
    #pragma unroll
    for (int rep = 0; rep < 5; ++rep) {
        int l = tid + rep*512;           // 2560 records
        int pp = l / NT, t = l - pp*NT;
        float4 v = tg4[l];
        sxy[t][pp] = make_float2(v.x, v.y);
    }
    __syncthreads();

    // ---- phase B: 2x2 register-tiled pairs, 4 t-slices (R11-proven shape) ----
    {
        const int tile = tid >> 2, slice = tid & 3;
        int A_, B_, C_, D_;
        bool offd = (tile < 120);
        if (offd) {
            // library sqrtf: must be exact on perfect squares (once/thread)
            float fs = sqrtf((float)(1 + 8*tile));
            int tj = (int)((1.0f + fs) * 0.5f);
            int ti = tile - ((tj*(tj-1)) >> 1);
            A_ = 2*ti; B_ = 2*ti+1; C_ = 2*tj; D_ = 2*tj+1;
        } else {
            int m = tile - 120;
            A_ = 4*m; B_ = 4*m+2; C_ = 4*m+1; D_ = 4*m+3;
        }
        float accAC = 0.0f, accAD = 0.0f, accBC = 0.0f, accBD = 0.0f;
        const int tbase = slice * 20;
        #pragma unroll 4
        for (int tt = 0; tt < 20; ++tt) {
            int t = tbase + tt;
            float2 va = sxy[t][A_], vb = sxy[t][B_];
            float2 vc = sxy[t][C_], vd = sxy[t][D_];
            float dx, dy;
            dx = va.x - vc.x; dy = va.y - vc.y; accAC += FSQRT(fmaf(dx,dx,dy*dy));
            dx = va.x - vd.x; dy = va.y - vd.y; accAD += FSQRT(fmaf(dx,dx,dy*dy));
            dx = vb.x - vc.x; dy = vb.y - vc.y; accBC += FSQRT(fmaf(dx,dx,dy*dy));
            dx = vb.x - vd.x; dy = vb.y - vd.y; accBD += FSQRT(fmaf(dx,dx,dy*dy));
        }
        const int qb = lane & ~3;
#define FOLD(acc) ((((acc) + __shfl((acc), qb+1)) + __shfl((acc), qb+2)) + __shfl((acc), qb+3))
        float fAC = FOLD(accAC);
        float fAD = FOLD(accAD);
        float fBC = FOLD(accBC);
        float fBD = FOLD(accBD);
#undef FOLD
        if (slice == 0) {
            const float inv = 1.0f / (float)NT;
            float e0 = fAC*inv, e1 = fAD*inv, e2 = fBC*inv, e3 = fBD*inv;
            sade[A_][C_] = e0; sade[C_][A_] = e0;
            if (e0 < thrM) { atomicOr(&wloc[A_], 1u<<C_); atomicOr(&wloc[C_], 1u<<A_); }
            sade[B_][D_] = e3; sade[D_][B_] = e3;
            if (e3 < thrM) { atomicOr(&wloc[B_], 1u<<D_); atomicOr(&wloc[D_], 1u<<B_); }
            if (offd) {
                sade[A_][D_] = e1; sade[D_][A_] = e1;
                if (e1 < thrM) { atomicOr(&wloc[A_], 1u<<D_); atomicOr(&wloc[D_], 1u<<A_); }
                sade[B_][C_] = e2; sade[C_][B_] = e2;
                if (e2 < thrM) { atomicOr(&wloc[B_], 1u<<C_); atomicOr(&wloc[C_], 1u<<B_); }
            }
        }
    }
    __syncthreads();

    // ---- phase C + outputs: waves 0-3 only (waves 4-7 exit; no outputs there) ----
    if (tid < 256) {
        // valid[] encoding detection (u8 bool / i32 / f32)
        bool fHit = (u0 == 0x3F800000u) || (u1 == 0x3F800000u);
        int nz0 = ((u0&0xFFu)!=0)+((u0&0xFF00u)!=0)+((u0&0xFF0000u)!=0)+((u0&0xFF000000u)!=0);
        int nz1 = ((u1&0xFFu)!=0)+((u1&0xFF00u)!=0)+((u1&0xFF0000u)!=0)+((u1&0xFF000000u)!=0);
        bool isF = __any(fHit), multi = __any(nz0 >= 2 || nz1 >= 2);
        int vflag;
        if (isF)        vflag = (((const float*)valid_raw)[blk] != 0.0f);
        else if (multi) vflag = (((const unsigned char*)valid_raw)[blk] != 0);
        else            vflag = (((const int*)valid_raw)[blk] != 0);

        unsigned wl = wloc[p];

        // greedy MTR scan: 5-level fmax reduce + ballot/ffs argmax (first-index tie-break)
        float carry = sc;
        int sel_0, sel_1, sel_2, sel_3, sel_4, sel_5;
#define GREEDY(SK) { \
        float vv = carry; \
        _Pragma("unroll") \
        for (int off = 16; off; off >>= 1) vv = fmaxf(vv, __shfl_xor(vv, off)); \
        unsigned long long mba = __ballot(carry == vv); \
        int bi = __ffsll((long long)mba) - 1; \
        SK = bi; \
        unsigned rbi = __shfl(wl, bi); \
        carry = (p == bi) ? -1.0f : (((rbi >> p) & 1u) ? carry*0.01f : carry); }
        GREEDY(sel_0) GREEDY(sel_1) GREEDY(sel_2) GREEDY(sel_3) GREEDY(sel_4) GREEDY(sel_5)
#undef GREEDY

        float q0 = __shfl(sc, sel_0), q1 = __shfl(sc, sel_1), q2 = __shfl(sc, sel_2);
        float q3 = __shfl(sc, sel_3), q4 = __shfl(sc, sel_4), q5 = __shfl(sc, sel_5);

        // MPA 6x6 within from LDS ADE matrix (lanes 0-14 of each wave, one pair each)
        int ii = (lane<5)?0 : (lane<9)?1 : (lane<12)?2 : (lane<14)?3 : 4;
        int jj = lane - ((ii==0)?-1 : (ii==1)?3 : (ii==2)?6 : (ii==3)?8 : 9);
        jj = (jj < 0) ? 0 : (jj > 5 ? 5 : jj);
        int pi = (ii==0)?sel_0:(ii==1)?sel_1:(ii==2)?sel_2:(ii==3)?sel_3:(ii==4)?sel_4:sel_5;
        int pj = (jj==0)?sel_0:(jj==1)?sel_1:(jj==2)?sel_2:(jj==3)?sel_3:(jj==4)?sel_4:sel_5;
        float ade15 = sade[pi][pj];
        bool within = (lane < 15) && (ade15 < thrQ);
        unsigned long long bal = __ballot(within);
#define B(i) ((unsigned)((bal >> (i)) & 1ull))
        unsigned w6_0 = (B(0)<<1)|(B(1)<<2)|(B(2)<<3)|(B(3)<<4)|(B(4)<<5);
        unsigned w6_1 = (B(0)<<0)|(B(5)<<2)|(B(6)<<3)|(B(7)<<4)|(B(8)<<5);
        unsigned w6_2 = (B(1)<<0)|(B(5)<<1)|(B(9)<<3)|(B(10)<<4)|(B(11)<<5);
        unsigned w6_3 = (B(2)<<0)|(B(6)<<1)|(B(9)<<2)|(B(12)<<4)|(B(13)<<5);
        unsigned w6_4 = (B(3)<<0)|(B(7)<<1)|(B(10)<<2)|(B(12)<<3)|(B(14)<<5);
        unsigned w6_5 = (B(4)<<0)|(B(8)<<1)|(B(11)<<2)|(B(13)<<3)|(B(14)<<4);
#undef B

        // stable ranks (argsort(-q), ties -> lower index)
#define GE(x,y) ((x) >= (y))
        bool a01=GE(q0,q1), a02=GE(q0,q2), a03=GE(q0,q3), a04=GE(q0,q4), a05=GE(q0,q5);
        bool a12=GE(q1,q2), a13=GE(q1,q3), a14=GE(q1,q4), a15=GE(q1,q5);
        bool a23=GE(q2,q3), a24=GE(q2,q4), a25=GE(q2,q5);
        bool a34=GE(q3,q4), a35=GE(q3,q5);
        bool a45=GE(q4,q5);
#undef GE
        int r0 = (!a01)+(!a02)+(!a03)+(!a04)+(!a05);
        int r1 = a01+(!a12)+(!a13)+(!a14)+(!a15);
        int r2 = a02+a12+(!a23)+(!a24)+(!a25);
        int r3 = a03+a13+a23+(!a34)+(!a35);
        int r4 = a04+a14+a24+a34+(!a45);
        int r5 = a05+a15+a25+a35+a45;

        // serial MPA scan, exact semantics, all-scalar
        const float sum6 = q0+q1+q2+q3+q4+q5;
        const float supv = 0.001f * sum6;
#define STEP(m) { \
        float ck = (r0==m)?q0:(r1==m)?q1:(r2==m)?q2:(r3==m)?q3:(r4==m)?q4:q5; \
        unsigned wk = (r0==m)?w6_0:(r1==m)?w6_1:(r2==m)?w6_2:(r3==m)?w6_3:(r4==m)?w6_4:w6_5; \
        bool sup = (((wk>>0)&1u)&&(q0>ck))||(((wk>>1)&1u)&&(q1>ck))||(((wk>>2)&1u)&&(q2>ck)) \
                 ||(((wk>>3)&1u)&&(q3>ck))||(((wk>>4)&1u)&&(q4>ck))||(((wk>>5)&1u)&&(q5>ck)); \
        bool go = vflag && sup; \
        q0 = (go&&(r0==m))?supv:q0; q1 = (go&&(r1==m))?supv:q1; q2 = (go&&(r2==m))?supv:q2; \
        q3 = (go&&(r3==m))?supv:q3; q4 = (go&&(r4==m))?supv:q4; q5 = (go&&(r5==m))?supv:q5; }
        STEP(0) STEP(1) STEP(2) STEP(3) STEP(4) STEP(5)
#undef STEP

        // softmax(1.25*ln q) via fast log/exp (outputs have 1.82 absmax margin)
        float g0 = __logf(q0)*1.25f, g1 = __logf(q1)*1.25f, g2 = __logf(q2)*1.25f;
        float g3 = __logf(q3)*1.25f, g4 = __logf(q4)*1.25f, g5 = __logf(q5)*1.25f;
        float mx = fmaxf(fmaxf(fmaxf(g0,g1),fmaxf(g2,g3)),fmaxf(g4,g5));
        float e0 = __expf(g0-mx), e1 = __expf(g1-mx), e2 = __expf(g2-mx);
        float e3 = __expf(g3-mx), e4 = __expf(g4-mx), e5 = __expf(g5-mx);
        float es = e0+e1+e2+e3+e4+e5;

        if (tid < NK) {       // wave 0: scores output
            float fv = (lane==0)?e0:(lane==1)?e1:(lane==2)?e2:(lane==3)?e3:(lane==4)?e4:e5;
            out[BASE3 + (size_t)blk*NK + lane] = fv / es;
        }
        if (tid < NT)         // waves 0-1: valid output
            out[BASE4 + (size_t)(s*NT + tid)*NA + a] = vflag ? 1.0f : 0.0f;

        // ---- phase D: traj outputs (sel in wave-uniform regs); gather from
        //      global (L2-hot from phase A) ----
        if (tid < 3*NT) {
            int t = tid / 3, kp = tid - t*3;
            int k0 = kp*2;
            int s0sel = (kp==0)?sel_0:(kp==1)?sel_2:sel_4;
            int s1sel = (kp==0)?sel_1:(kp==1)?sel_3:sel_5;
            float4 v0 = tg4[(size_t)s0sel*NT + t];
            float4 v1 = tg4[(size_t)s1sel*NT + t];
            size_t ob = (((size_t)(s*NT + t)*NA + a)*NK + k0);   // float2-unit index (even)
            *(float4*)((float2*)out + ob) = make_float4(v0.x, v0.y, v1.x, v1.y);
            *(float2*)(out + BASE1 + ob) = make_float2(v0.z, v1.z);
            *(float2*)(out + BASE2 + ob) = make_float2(v0.w, v1.w);
        }
    }
}

extern "C" void kernel_launch(void* const* d_in, const int* in_sizes, int n_in,
                              void* d_out, int out_size, void* d_ws, size_t ws_size,
                              hipStream_t stream) {
    const void*  valid  = d_in[0];
    const float* scores = (const float*)d_in[1];
    const float* trajs  = (const float*)d_in[2];
    const float* atype  = (const float*)d_in[3];
    k_fused<<<NAG, 512, 0, stream>>>(valid, scores, trajs, atype, (float*)d_out);
}